// Round 1
// baseline (3238.852 us; speedup 1.0000x reference)
//
#include <hip/hip_runtime.h>
#include <stdint.h>

// TopK similarity: 4096 queries x (4096 rows x 128 vecs x 128 dim), top-16 rows.
// Pipeline: K0 fp32->bf16 table | K1 bf16-MFMA coarse scores + per-row max +
// per-16-row-chunk top-8 | K2 merge -> top-24 rows/query + bucket by row |
// K3 exact fp32 refine per row-bucket (atomicMax) | K4 sort + gather outputs.
// ws assumption: >= ~209 MiB.

typedef __attribute__((ext_vector_type(8))) short short8;
typedef __attribute__((ext_vector_type(4))) float floatx4;
typedef unsigned long long u64;
typedef unsigned int u32;

#define NQ 4096
#define NR 4096
#define NV 128
#define ND 128
#define KTOP 16
#define RC 16            // rows per coarse chunk
#define NCHUNK (NR / RC) // 256
#define CPC 8            // candidates kept per (query, chunk)
#define CSEL 24          // refined candidates per query (>= KTOP with margin)
#define BCAP 1024        // bucket capacity per table row

__device__ __forceinline__ unsigned short f2bf(float f) {
  u32 u = __float_as_uint(f);
  u32 r = u + 0x7FFFu + ((u >> 16) & 1u); // round-to-nearest-even
  return (unsigned short)(r >> 16);
}
__device__ __forceinline__ u32 key_of(float s) { // monotone float->u32
  u32 b = __float_as_uint(s);
  return (b & 0x80000000u) ? ~b : (b | 0x80000000u);
}
__device__ __forceinline__ float unkey(u32 k) {
  u32 b = (k & 0x80000000u) ? (k & 0x7FFFFFFFu) : ~k;
  return __uint_as_float(b);
}

// ---------------- K0: table fp32 -> bf16 ----------------
__global__ void k0_convert(const float* __restrict__ t, unsigned short* __restrict__ o) {
  size_t i = ((size_t)blockIdx.x * 256 + threadIdx.x) * 4;
  float4 v = *reinterpret_cast<const float4*>(t + i);
  ushort4 r;
  r.x = f2bf(v.x); r.y = f2bf(v.y); r.z = f2bf(v.z); r.w = f2bf(v.w);
  *reinterpret_cast<ushort4*>(o + i) = r;
}

// ---------------- K1: coarse bf16 MFMA scores + per-row max + chunk top-8 ----
// Grid (32 qblocks, 256 chunks), 256 threads. WG = 128 queries x 16 rows.
// A-frags (queries, bf16) held in registers for the whole chunk.
__launch_bounds__(256, 2)
__global__ void k1_coarse(const float* __restrict__ Q, const unsigned short* __restrict__ T16,
                          u64* __restrict__ cand) {
  __shared__ short Blds[128 * 136];   // one table row, pitch 136 bf16 (bank-safe)
  __shared__ float aux[4 * 128];      // per-wave partial row-max (v stuffed in bits)
  __shared__ u64 rowarr[RC * 128];    // per-row packed (key<<32 | fid)

  const int tid = threadIdx.x;
  const int wave = tid >> 6;
  const int lane = tid & 63;
  const int l15 = lane & 15;
  const int q8 = lane >> 4;
  const int qblock = blockIdx.x;
  const int chunk = blockIdx.y;

  // Load A fragments once: A[m=lane&15][k=(lane>>4)*8+j], fp32 -> bf16.
  short8 afrag[8][4];
#pragma unroll
  for (int qt = 0; qt < 8; qt++) {
    const float* qp = Q + (size_t)(qblock * 128 + qt * 16 + l15) * 128 + q8 * 8;
#pragma unroll
    for (int ks = 0; ks < 4; ks++) {
      float4 x = *reinterpret_cast<const float4*>(qp + ks * 32);
      float4 y = *reinterpret_cast<const float4*>(qp + ks * 32 + 4);
      short8 a;
      a[0] = (short)f2bf(x.x); a[1] = (short)f2bf(x.y);
      a[2] = (short)f2bf(x.z); a[3] = (short)f2bf(x.w);
      a[4] = (short)f2bf(y.x); a[5] = (short)f2bf(y.y);
      a[6] = (short)f2bf(y.z); a[7] = (short)f2bf(y.w);
      afrag[qt][ks] = a;
    }
  }

  for (int rl = 0; rl < RC; rl++) {
    const int row = chunk * RC + rl;
    __syncthreads();
    { // stage one table row (128 vecs x 128 k bf16) into LDS
      const unsigned short* src = T16 + (size_t)row * (NV * ND);
#pragma unroll
      for (int i = 0; i < 8; i++) {
        int e = i * 2048 + tid * 8;
        int v = e >> 7, k = e & 127;
        *reinterpret_cast<short8*>(&Blds[v * 136 + k]) =
            *reinterpret_cast<const short8*>(src + e);
      }
    }
    __syncthreads();

    floatx4 acc[8][2];
#pragma unroll
    for (int qt = 0; qt < 8; qt++) { acc[qt][0] = 0; acc[qt][1] = 0; }

    const short* bbase = &Blds[(wave * 32 + l15) * 136 + q8 * 8];
#pragma unroll
    for (int ks = 0; ks < 4; ks++) {
      short8 b0 = *reinterpret_cast<const short8*>(bbase + ks * 32);
      short8 b1 = *reinterpret_cast<const short8*>(bbase + 16 * 136 + ks * 32);
#pragma unroll
      for (int qt = 0; qt < 8; qt++) {
        acc[qt][0] = __builtin_amdgcn_mfma_f32_16x16x32_bf16(afrag[qt][ks], b0, acc[qt][0], 0, 0, 0);
        acc[qt][1] = __builtin_amdgcn_mfma_f32_16x16x32_bf16(afrag[qt][ks], b1, acc[qt][1], 0, 0, 0);
      }
    }

    // Per-row max over v: stuff v into low 7 mantissa bits -> pure fmax reduce.
    const u32 vb = (u32)(wave * 32 + l15);
#pragma unroll
    for (int qt = 0; qt < 8; qt++) {
#pragma unroll
      for (int reg = 0; reg < 4; reg++) {
        float p0 = __uint_as_float((__float_as_uint(acc[qt][0][reg]) & 0xFFFFFF80u) | vb);
        float p1 = __uint_as_float((__float_as_uint(acc[qt][1][reg]) & 0xFFFFFF80u) | (vb + 16u));
        float m = fmaxf(p0, p1);
#pragma unroll
        for (int off = 1; off < 16; off <<= 1) m = fmaxf(m, __shfl_xor(m, off, 64));
        if (l15 == 0) aux[wave * 128 + qt * 16 + q8 * 4 + reg] = m;
      }
    }
    __syncthreads();
    if (tid < 128) { // merge 4 waves' v-ranges; thread t owns query column t
      float m = fmaxf(fmaxf(aux[tid], aux[128 + tid]), fmaxf(aux[256 + tid], aux[384 + tid]));
      u32 b = __float_as_uint(m);
      u32 v = b & 127u;
      float sc = __uint_as_float(b & 0xFFFFFF80u);
      rowarr[rl * 128 + tid] = ((u64)key_of(sc) << 32) | (u32)(row * 128 + v);
    }
  }
  __syncthreads();
  if (tid < 128) { // per-query top-8 of this chunk's 16 rows
    u64 a[CPC];
#pragma unroll
    for (int i = 0; i < CPC; i++) a[i] = 0;
    for (int rl = 0; rl < RC; rl++) {
      u64 x = rowarr[rl * 128 + tid];
      if (x > a[CPC - 1]) {
        int p = CPC - 1;
        while (p > 0 && a[p - 1] < x) { a[p] = a[p - 1]; p--; }
        a[p] = x;
      }
    }
    const int q = qblock * 128 + tid;
    u64* dst = cand + (size_t)q * (NCHUNK * CPC) + chunk * CPC;
#pragma unroll
    for (int i = 0; i < CPC; i++) dst[i] = a[i];
  }
}

// ---------------- K2: merge 2048 candidates -> top-24 rows/query + buckets ---
__global__ void k2_select(const u64* __restrict__ cand, u64* __restrict__ refined,
                          u32* __restrict__ cnt, u32* __restrict__ bucket) {
  __shared__ u64 wbest[4];
  const int q = blockIdx.x;
  const int tid = threadIdx.x;
  const int wave = tid >> 6, lane = tid & 63;
  u64 e[8];
  const u64* base = cand + (size_t)q * (NCHUNK * CPC);
#pragma unroll
  for (int i = 0; i < 8; i++) e[i] = base[i * 256 + tid];
  u32 used = 0;
  for (int j = 0; j < CSEL; j++) {
    u64 loc = 0;
#pragma unroll
    for (int i = 0; i < 8; i++)
      if (!(used & (1u << i)) && e[i] > loc) loc = e[i];
#pragma unroll
    for (int off = 1; off < 64; off <<= 1) {
      u64 o = __shfl_xor(loc, off, 64);
      if (o > loc) loc = o;
    }
    if (lane == 0) wbest[wave] = loc;
    __syncthreads();
    u64 W = wbest[0];
    if (wbest[1] > W) W = wbest[1];
    if (wbest[2] > W) W = wbest[2];
    if (wbest[3] > W) W = wbest[3];
#pragma unroll
    for (int i = 0; i < 8; i++)
      if (e[i] == W) used |= (1u << i); // fid unique -> exactly one owner
    if (tid == 0) {
      refined[(size_t)q * CSEL + j] = 0; // sentinel; K3 atomicMax's over it
      u32 fid = (u32)W;
      u32 row = fid >> 7;
      u32 slot = atomicAdd(cnt + row, 1u);
      if (slot < BCAP) bucket[(size_t)row * BCAP + slot] = ((u32)q << 5) | (u32)j;
    }
    __syncthreads();
  }
}

// ---------------- K3: exact fp32 refine, bucketed by table row ---------------
// Grid 4096 (one WG per row), 128 threads. Row in swizzled LDS (64 KiB).
__global__ void k3_refine(const float* __restrict__ Q, const float* __restrict__ table,
                          const u32* __restrict__ cnt, const u32* __restrict__ bucket,
                          u64* __restrict__ refined) {
  __shared__ float rowv[128 * 128]; // float4 chunk d4 of vec v at (d4 ^ (v&31))
  const int row = blockIdx.x;
  const int tid = threadIdx.x; // 0..127
  const int lane = tid & 63;
  u32 n = cnt[row];
  if (n > BCAP) n = BCAP;
  if (n == 0) return;
  const float* src = table + (size_t)row * (NV * ND);
#pragma unroll
  for (int i = 0; i < 32; i++) {
    int idx = i * 512 + tid * 4;
    int v = idx >> 7;
    int d4 = tid & 31;
    *reinterpret_cast<float4*>(&rowv[v * 128 + ((d4 ^ (v & 31)) << 2)]) =
        *reinterpret_cast<const float4*>(src + idx);
  }
  __syncthreads();
  const int v = tid; // each thread owns one vector of the row
  const int sw = v & 31;
  for (u32 ei = 0; ei < n; ei++) {
    u32 ent = bucket[(size_t)row * BCAP + ei];
    u32 q = ent >> 5, j = ent & 31u;
    float4 qreg = *reinterpret_cast<const float4*>(Q + (size_t)q * 128 + (lane & 31) * 4);
    float acc = 0.f;
#pragma unroll
    for (int d4 = 0; d4 < 32; d4++) {
      float4 rv = *reinterpret_cast<const float4*>(&rowv[v * 128 + ((d4 ^ sw) << 2)]);
      float qx = __shfl(qreg.x, d4, 32);
      float qy = __shfl(qreg.y, d4, 32);
      float qz = __shfl(qreg.z, d4, 32);
      float qw = __shfl(qreg.w, d4, 32);
      acc = fmaf(rv.x, qx, acc); acc = fmaf(rv.y, qy, acc);
      acc = fmaf(rv.z, qz, acc); acc = fmaf(rv.w, qw, acc);
    }
    // wave argmax (smaller v wins ties via 127-v packing), then global atomicMax
    u64 p = ((u64)key_of(acc) << 32) | (u32)(127 - v);
#pragma unroll
    for (int off = 1; off < 64; off <<= 1) {
      u64 o = __shfl_xor(p, off, 64);
      if (o > p) p = o;
    }
    if (lane == 0) {
      u32 vbest = 127u - (u32)(p & 0xFFFFFFFFu);
      u64 packed = ((p >> 32) << 32) | (u32)(row * 128 + vbest);
      atomicMax(reinterpret_cast<unsigned long long*>(&refined[(size_t)q * CSEL + j]), packed);
    }
  }
}

// ---------------- K4: sort 24 -> top-16, gather values/scores/ids ------------
__global__ void k4_finalize(const float* __restrict__ table, const u64* __restrict__ refined,
                            float* __restrict__ out) {
  __shared__ u64 arr[CSEL];
  __shared__ u32 fids[KTOP];
  __shared__ float scs[KTOP];
  const int q = blockIdx.x;
  const int tid = threadIdx.x;
  if (tid < CSEL) arr[tid] = refined[(size_t)q * CSEL + tid];
  __syncthreads();
  if (tid == 0) {
    for (int i = 1; i < CSEL; i++) { // insertion sort, descending u64 =
      u64 x = arr[i]; int p = i;     // (score desc, then larger fid) = ref order
      while (p > 0 && arr[p - 1] < x) { arr[p] = arr[p - 1]; p--; }
      arr[p] = x;
    }
    for (int i = 0; i < KTOP; i++) {
      fids[i] = (u32)arr[i];
      scs[i] = unkey((u32)(arr[i] >> 32));
    }
  }
  __syncthreads();
  const int i = tid >> 4, sub = tid & 15;
  const float* src = table + (size_t)fids[i] * 128 + sub * 8;
  float* dst = out + ((size_t)q * KTOP + i) * 128 + sub * 8;
  *reinterpret_cast<float4*>(dst) = *reinterpret_cast<const float4*>(src);
  *reinterpret_cast<float4*>(dst + 4) = *reinterpret_cast<const float4*>(src + 4);
  if (tid < KTOP) {
    out[8388608 + (size_t)q * KTOP + tid] = scs[tid];
    out[8388608 + 65536 + (size_t)q * KTOP + tid] = (float)fids[tid];
  }
}

extern "C" void kernel_launch(void* const* d_in, const int* in_sizes, int n_in,
                              void* d_out, int out_size, void* d_ws, size_t ws_size,
                              hipStream_t stream) {
  (void)in_sizes; (void)n_in; (void)out_size; (void)ws_size;
  const float* Q = (const float*)d_in[0];
  const float* T = (const float*)d_in[1];
  float* out = (float*)d_out;
  char* ws = (char*)d_ws;
  // ws layout (total ~208.8 MiB)
  unsigned short* T16 = (unsigned short*)ws;                                   // 128 MiB
  u64* cand    = (u64*)(ws + 134217728);                                       //  64 MiB
  u32* cnt     = (u32*)(ws + 134217728 + 67108864);                            //  16 KiB
  u32* bucket  = (u32*)(ws + 134217728 + 67108864 + 16384);                    //  16 MiB
  u64* refined = (u64*)(ws + 134217728 + 67108864 + 16384 + 16777216);         // 768 KiB

  hipMemsetAsync(cnt, 0, NR * sizeof(u32), stream);
  k0_convert<<<65536, 256, 0, stream>>>(T, T16);
  k1_coarse<<<dim3(32, 256), 256, 0, stream>>>(Q, T16, cand);
  k2_select<<<NQ, 256, 0, stream>>>(cand, refined, cnt, bucket);
  k3_refine<<<NR, 128, 0, stream>>>(Q, T, cnt, bucket, refined);
  k4_finalize<<<NQ, 256, 0, stream>>>(T, refined, out);
}

// Round 2
// 1745.259 us; speedup vs baseline: 1.8558x; 1.8558x over previous
//
#include <hip/hip_runtime.h>
#include <stdint.h>

// TopK similarity: 4096 queries x (4096 rows x 128 vecs x 128 dim), top-16 rows.
// Pipeline: K0 fp32->bf16 table | K1 bf16-MFMA coarse per-row max + chunk top-8
// (A=vectors from LDS, B=queries in regs; reduce is in-register fmax tree) |
// K2 wave-per-query merge -> top-24 rows + row buckets | K3 exact fp32 refine
// per row-bucket (scalarized q, atomicMax) | K4 sort + gather outputs.
// ws assumption: >= ~209 MiB.

typedef __attribute__((ext_vector_type(8))) short short8;
typedef __attribute__((ext_vector_type(4))) float floatx4;
typedef unsigned long long u64;
typedef unsigned int u32;

#define NQ 4096
#define NR 4096
#define NV 128
#define ND 128
#define KTOP 16
#define RC 16            // rows per coarse chunk
#define NCHUNK (NR / RC) // 256
#define CPC 8            // candidates kept per (query, chunk)
#define CSEL 24          // refined candidates per query
#define BCAP 1024        // bucket capacity per table row

__device__ __forceinline__ unsigned short f2bf(float f) {
  u32 u = __float_as_uint(f);
  u32 r = u + 0x7FFFu + ((u >> 16) & 1u); // round-to-nearest-even
  return (unsigned short)(r >> 16);
}
__device__ __forceinline__ u32 key_of(float s) { // monotone float->u32
  u32 b = __float_as_uint(s);
  return (b & 0x80000000u) ? ~b : (b | 0x80000000u);
}
__device__ __forceinline__ float unkey(u32 k) {
  u32 b = (k & 0x80000000u) ? (k & 0x7FFFFFFFu) : ~k;
  return __uint_as_float(b);
}

// ---------------- K0: table fp32 -> bf16 ----------------
__global__ void k0_convert(const float* __restrict__ t, unsigned short* __restrict__ o) {
  size_t i = ((size_t)blockIdx.x * 256 + threadIdx.x) * 4;
  float4 v = *reinterpret_cast<const float4*>(t + i);
  ushort4 r;
  r.x = f2bf(v.x); r.y = f2bf(v.y); r.z = f2bf(v.z); r.w = f2bf(v.w);
  *reinterpret_cast<ushort4*>(o + i) = r;
}

// ---------------- K1: coarse bf16 MFMA per-row max + chunk top-8 ------------
// Grid (32 qblocks, 256 chunks), 256 threads. WG = 128 queries x 16 rows.
// A = table vectors (LDS, XOR-swizzled), B = queries (regs, whole chunk).
// C layout: col=lane&15 = query, row=quad*4+reg = vector -> max over v is
// 7 in-reg fmax + 2 xor-shuffles. Coarse argmax-v not needed (K3 refines).
__launch_bounds__(256, 2)
__global__ void k1_coarse(const float* __restrict__ Q, const unsigned short* __restrict__ T16,
                          u64* __restrict__ cand) {
  __shared__ short Blds[128 * 128];       // 32 KiB, 8-short blocks XOR-swizzled
  __shared__ float rowmax4[RC][4][128];   // 32 KiB per-(row,wave,query) partial max

  const int tid = threadIdx.x;
  const int wave = tid >> 6;
  const int lane = tid & 63;
  const int l15 = lane & 15;
  const int q8 = lane >> 4; // quad
  const int qblock = blockIdx.x;
  const int chunk = blockIdx.y;

  // B fragments: queries, fp32 -> bf16. B[n=lane&15][k=quad*8+j].
  short8 bfrag[8][4];
#pragma unroll
  for (int qt = 0; qt < 8; qt++) {
    const float* qp = Q + (size_t)(qblock * 128 + qt * 16 + l15) * 128 + q8 * 8;
#pragma unroll
    for (int ks = 0; ks < 4; ks++) {
      float4 x = *reinterpret_cast<const float4*>(qp + ks * 32);
      float4 y = *reinterpret_cast<const float4*>(qp + ks * 32 + 4);
      short8 b;
      b[0] = (short)f2bf(x.x); b[1] = (short)f2bf(x.y);
      b[2] = (short)f2bf(x.z); b[3] = (short)f2bf(x.w);
      b[4] = (short)f2bf(y.x); b[5] = (short)f2bf(y.y);
      b[6] = (short)f2bf(y.z); b[7] = (short)f2bf(y.w);
      bfrag[qt][ks] = b;
    }
  }

  // Staging addressing: element e = i*2048 + tid*8 of the row.
  // v = e>>7 = i*16 + (tid>>4), k-block kb = tid&15; store kb' = kb ^ (v&15).
  const int stbase = ((tid >> 4) * 128) + 8 * ((tid & 15) ^ (tid >> 4));
  const unsigned short* src0 = T16 + (size_t)(chunk * RC) * (NV * ND);
  short8 pre[8];
#pragma unroll
  for (int i = 0; i < 8; i++)
    pre[i] = *reinterpret_cast<const short8*>(src0 + i * 2048 + tid * 8);

  for (int rl = 0; rl < RC; rl++) {
    if (rl) __syncthreads(); // W-A-R: prior A-reads done before overwrite
#pragma unroll
    for (int i = 0; i < 8; i++)
      *reinterpret_cast<short8*>(&Blds[i * 2048 + stbase]) = pre[i];
    __syncthreads();         // R-A-W
    if (rl < RC - 1) {       // prefetch next row during compute
      const unsigned short* src = T16 + (size_t)(chunk * RC + rl + 1) * (NV * ND);
#pragma unroll
      for (int i = 0; i < 8; i++)
        pre[i] = *reinterpret_cast<const short8*>(src + i * 2048 + tid * 8);
    }

    floatx4 acc[8][2];
#pragma unroll
    for (int qt = 0; qt < 8; qt++) { acc[qt][0] = 0; acc[qt][1] = 0; }

#pragma unroll
    for (int ks = 0; ks < 4; ks++) {
      const int kb = ks * 4 + q8;          // k-block index 0..15
      const int kk = 8 * (kb ^ l15);       // swizzled k offset (shorts)
      short8 a0 = *reinterpret_cast<const short8*>(&Blds[(wave * 32 + l15) * 128 + kk]);
      short8 a1 = *reinterpret_cast<const short8*>(&Blds[(wave * 32 + 16 + l15) * 128 + kk]);
#pragma unroll
      for (int qt = 0; qt < 8; qt++) {
        acc[qt][0] = __builtin_amdgcn_mfma_f32_16x16x32_bf16(a0, bfrag[qt][ks], acc[qt][0], 0, 0, 0);
        acc[qt][1] = __builtin_amdgcn_mfma_f32_16x16x32_bf16(a1, bfrag[qt][ks], acc[qt][1], 0, 0, 0);
      }
    }

    // Reduce over v: 8 regs in-register, then quads via 2 xor-shuffles.
#pragma unroll
    for (int qt = 0; qt < 8; qt++) {
      float m01 = fmaxf(acc[qt][0][0], acc[qt][0][1]);
      float m23 = fmaxf(acc[qt][0][2], acc[qt][0][3]);
      float n01 = fmaxf(acc[qt][1][0], acc[qt][1][1]);
      float n23 = fmaxf(acc[qt][1][2], acc[qt][1][3]);
      float m = fmaxf(fmaxf(m01, m23), fmaxf(n01, n23));
      m = fmaxf(m, __shfl_xor(m, 16, 64));
      m = fmaxf(m, __shfl_xor(m, 32, 64));
      if (lane < 16) rowmax4[rl][wave][qt * 16 + lane] = m;
    }
  }
  __syncthreads();

  if (tid < 128) { // per-query top-8 rows of this chunk
    u64 a[CPC];
#pragma unroll
    for (int i = 0; i < CPC; i++) a[i] = 0;
    for (int rl = 0; rl < RC; rl++) {
      float m = fmaxf(fmaxf(rowmax4[rl][0][tid], rowmax4[rl][1][tid]),
                      fmaxf(rowmax4[rl][2][tid], rowmax4[rl][3][tid]));
      u64 x = ((u64)key_of(m) << 32) | (u32)(chunk * RC + rl);
      if (x > a[CPC - 1]) {
#pragma unroll
        for (int p = 0; p < CPC; p++) { // sorted-desc bubble, static indices
          u64 mx = a[p] > x ? a[p] : x;
          u64 mn = a[p] > x ? x : a[p];
          a[p] = mx; x = mn;
        }
      }
    }
    const int q = qblock * 128 + tid;
    u64* dst = cand + (size_t)q * (NCHUNK * CPC) + chunk * CPC;
#pragma unroll
    for (int i = 0; i < CPC; i++) dst[i] = a[i];
  }
}

// ---------------- K2: wave-per-query merge -> top-24 rows + buckets ----------
// Block = 64 (one wave, no barriers). Each lane filters 32 entries to a local
// sorted top-12; 24 rounds of wave-argmax pop. Entries are distinct u64s
// (distinct rows), so the winner lane is unique.
__global__ void k2_select(const u64* __restrict__ cand, u64* __restrict__ refined,
                          u32* __restrict__ cnt, u32* __restrict__ bucket) {
  const int q = blockIdx.x;
  const int lane = threadIdx.x;
  const u64* base = cand + (size_t)q * (NCHUNK * CPC);
  u64 a[12];
#pragma unroll
  for (int i = 0; i < 12; i++) a[i] = 0;
  for (int i = 0; i < 32; i++) {
    u64 x = base[i * 64 + lane];
    if (x > a[11]) {
#pragma unroll
      for (int p = 0; p < 12; p++) {
        u64 mx = a[p] > x ? a[p] : x;
        u64 mn = a[p] > x ? x : a[p];
        a[p] = mx; x = mn;
      }
    }
  }
  if (lane < CSEL) refined[(size_t)q * CSEL + lane] = 0; // sentinel for K3

  for (int j = 0; j < CSEL; j++) {
    u64 head = a[0];
    u64 W = head;
#pragma unroll
    for (int off = 1; off < 64; off <<= 1) {
      u64 o = __shfl_xor(W, off, 64);
      if (o > W) W = o;
    }
    if (head == W) { // unique winner lane: pop + emit bucket entry
#pragma unroll
      for (int p = 0; p < 11; p++) a[p] = a[p + 1];
      a[11] = 0;
      u32 row = (u32)W & 4095u;
      u32 slot = atomicAdd(cnt + row, 1u);
      if (slot < BCAP) bucket[(size_t)row * BCAP + slot] = ((u32)q << 5) | (u32)j;
    }
  }
}

// ---------------- K3: exact fp32 refine, bucketed by table row ---------------
// Grid 4096 (one WG per row), 256 threads (2 entries in flight). Row in
// swizzled LDS (64 KiB); q scalarized via readfirstlane -> s_loads.
__global__ void k3_refine(const float* __restrict__ Q, const float* __restrict__ table,
                          const u32* __restrict__ cnt, const u32* __restrict__ bucket,
                          u64* __restrict__ refined) {
  __shared__ float rowv[128 * 128]; // float4 chunk d4 of vec v at (d4 ^ (v&31))
  const int row = blockIdx.x;
  const int tid = threadIdx.x; // 0..255
  u32 n = cnt[row];
  if (n > BCAP) n = BCAP;
  if (n == 0) return;
  const float* src = table + (size_t)row * (NV * ND);
#pragma unroll
  for (int i = 0; i < 16; i++) {
    int idx = i * 1024 + tid * 4;
    int v = idx >> 7;
    int d4 = tid & 31;
    *reinterpret_cast<float4*>(&rowv[v * 128 + ((d4 ^ (v & 31)) << 2)]) =
        *reinterpret_cast<const float4*>(src + idx);
  }
  __syncthreads();
  const int v = tid & 127; // vector owned by this thread
  const int lane = tid & 63;
  const int sw = v & 31;
  for (u32 ei = (u32)(tid >> 7); ei < n; ei += 2) {
    u32 ent = __builtin_amdgcn_readfirstlane(bucket[(size_t)row * BCAP + ei]);
    u32 q = ent >> 5, j = ent & 31u;
    const float* qp = Q + (size_t)q * 128; // uniform -> scalar loads
    float acc = 0.f;
#pragma unroll
    for (int d4 = 0; d4 < 32; d4++) { // strict sequential order (matches ref)
      float4 rv = *reinterpret_cast<const float4*>(&rowv[v * 128 + ((d4 ^ sw) << 2)]);
      acc = fmaf(rv.x, qp[d4 * 4 + 0], acc);
      acc = fmaf(rv.y, qp[d4 * 4 + 1], acc);
      acc = fmaf(rv.z, qp[d4 * 4 + 2], acc);
      acc = fmaf(rv.w, qp[d4 * 4 + 3], acc);
    }
    // wave argmax (smaller v wins ties), then global atomicMax
    u64 p = ((u64)key_of(acc) << 32) | (u32)(127 - v);
#pragma unroll
    for (int off = 1; off < 64; off <<= 1) {
      u64 o = __shfl_xor(p, off, 64);
      if (o > p) p = o;
    }
    if (lane == 0) {
      u32 vbest = 127u - (u32)(p & 0xFFFFFFFFu);
      u64 packed = ((p >> 32) << 32) | (u32)(row * 128 + vbest);
      atomicMax(reinterpret_cast<unsigned long long*>(&refined[(size_t)q * CSEL + j]), packed);
    }
  }
}

// ---------------- K4: sort 24 -> top-16, gather values/scores/ids ------------
__global__ void k4_finalize(const float* __restrict__ table, const u64* __restrict__ refined,
                            float* __restrict__ out) {
  __shared__ u64 arr[CSEL];
  __shared__ u32 fids[KTOP];
  __shared__ float scs[KTOP];
  const int q = blockIdx.x;
  const int tid = threadIdx.x;
  if (tid < CSEL) arr[tid] = refined[(size_t)q * CSEL + tid];
  __syncthreads();
  if (tid == 0) {
    for (int i = 1; i < CSEL; i++) { // insertion sort desc = ref order
      u64 x = arr[i]; int p = i;
      while (p > 0 && arr[p - 1] < x) { arr[p] = arr[p - 1]; p--; }
      arr[p] = x;
    }
    for (int i = 0; i < KTOP; i++) {
      fids[i] = (u32)arr[i];
      scs[i] = unkey((u32)(arr[i] >> 32));
    }
  }
  __syncthreads();
  const int i = tid >> 4, sub = tid & 15;
  const float* src = table + (size_t)fids[i] * 128 + sub * 8;
  float* dst = out + ((size_t)q * KTOP + i) * 128 + sub * 8;
  *reinterpret_cast<float4*>(dst) = *reinterpret_cast<const float4*>(src);
  *reinterpret_cast<float4*>(dst + 4) = *reinterpret_cast<const float4*>(src + 4);
  if (tid < KTOP) {
    out[8388608 + (size_t)q * KTOP + tid] = scs[tid];
    out[8388608 + 65536 + (size_t)q * KTOP + tid] = (float)fids[tid];
  }
}

extern "C" void kernel_launch(void* const* d_in, const int* in_sizes, int n_in,
                              void* d_out, int out_size, void* d_ws, size_t ws_size,
                              hipStream_t stream) {
  (void)in_sizes; (void)n_in; (void)out_size; (void)ws_size;
  const float* Q = (const float*)d_in[0];
  const float* T = (const float*)d_in[1];
  float* out = (float*)d_out;
  char* ws = (char*)d_ws;
  // ws layout (total ~209 MiB)
  unsigned short* T16 = (unsigned short*)ws;                                   // 128 MiB
  u64* cand    = (u64*)(ws + 134217728);                                       //  64 MiB
  u32* cnt     = (u32*)(ws + 134217728 + 67108864);                            //  16 KiB
  u32* bucket  = (u32*)(ws + 134217728 + 67108864 + 16384);                    //  16 MiB
  u64* refined = (u64*)(ws + 134217728 + 67108864 + 16384 + 16777216);         // 768 KiB

  hipMemsetAsync(cnt, 0, NR * sizeof(u32), stream);
  k0_convert<<<65536, 256, 0, stream>>>(T, T16);
  k1_coarse<<<dim3(32, 256), 256, 0, stream>>>(Q, T16, cand);
  k2_select<<<NQ, 64, 0, stream>>>(cand, refined, cnt, bucket);
  k3_refine<<<NR, 256, 0, stream>>>(Q, T, cnt, bucket, refined);
  k4_finalize<<<NQ, 256, 0, stream>>>(T, refined, out);
}

// Round 3
// 1216.176 us; speedup vs baseline: 2.6631x; 1.4350x over previous
//
#include <hip/hip_runtime.h>
#include <stdint.h>

// TopK similarity: 4096 queries x (4096 rows x 128 vecs x 128 dim), top-16 rows.
// K0 fp32->bf16 table | K1 bf16 32x32x16 MFMA coarse per-row max + chunk top-8
// (wave owns 32 queries; whole row staged via global_load_lds w/ source-side
// XOR swizzle, double-buffered; top-8 kept per-lane in registers) |
// K2 wave-per-query merge -> top-24 rows + row buckets | K3 exact fp32 refine
// per row-bucket (scalarized q, atomicMax) | K4 sort + gather outputs.
// ws assumption: >= ~209 MiB.

typedef __attribute__((ext_vector_type(8))) short short8;
typedef __attribute__((ext_vector_type(4))) float floatx4;
typedef __attribute__((ext_vector_type(16))) float floatx16;
typedef unsigned long long u64;
typedef unsigned int u32;

#define NQ 4096
#define NR 4096
#define NV 128
#define ND 128
#define KTOP 16
#define RC 16            // rows per coarse chunk
#define NCHUNK (NR / RC) // 256
#define CPC 8            // candidates kept per (query, chunk)
#define CSEL 24          // refined candidates per query
#define BCAP 1024        // bucket capacity per table row

__device__ __forceinline__ unsigned short f2bf(float f) {
  u32 u = __float_as_uint(f);
  u32 r = u + 0x7FFFu + ((u >> 16) & 1u); // round-to-nearest-even
  return (unsigned short)(r >> 16);
}
__device__ __forceinline__ u32 key_of(float s) { // monotone float->u32
  u32 b = __float_as_uint(s);
  return (b & 0x80000000u) ? ~b : (b | 0x80000000u);
}
__device__ __forceinline__ float unkey(u32 k) {
  u32 b = (k & 0x80000000u) ? (k & 0x7FFFFFFFu) : ~k;
  return __uint_as_float(b);
}
__device__ __forceinline__ void glds16(const void* g, void* l) {
  __builtin_amdgcn_global_load_lds(
      (const __attribute__((address_space(1))) unsigned int*)g,
      (__attribute__((address_space(3))) unsigned int*)l, 16, 0, 0);
}

// ---------------- K0: table fp32 -> bf16 ----------------
__global__ void k0_convert(const float* __restrict__ t, unsigned short* __restrict__ o) {
  size_t i = ((size_t)blockIdx.x * 256 + threadIdx.x) * 4;
  float4 v = *reinterpret_cast<const float4*>(t + i);
  ushort4 r;
  r.x = f2bf(v.x); r.y = f2bf(v.y); r.z = f2bf(v.z); r.w = f2bf(v.w);
  *reinterpret_cast<ushort4*>(o + i) = r;
}

// ---------------- K1: coarse MFMA per-row max + chunk top-8 ------------------
// Grid (32 qblocks, 256 chunks), 256 threads. Wave w owns queries w*32..w*32+31
// (bfrag 32 VGPRs) and scans all 128 vectors of each row via 32x32x16 MFMA.
// Row staged to LDS by global_load_lds (16B), XOR swizzle applied on the
// GLOBAL source address (DMA dst is lane*16-contiguous), double-buffered.
__launch_bounds__(256, 2)
__global__ void k1_coarse(const float* __restrict__ Q, const unsigned short* __restrict__ T16,
                          u64* __restrict__ cand) {
  __shared__ short Blds[2][128 * 128]; // 2 x 32 KiB

  const int tid = threadIdx.x;
  const int wave = tid >> 6;
  const int lane = tid & 63;
  const int l31 = lane & 31;
  const int l15 = lane & 15;
  const int half = lane >> 5;
  const int qblock = blockIdx.x;
  const int chunk = blockIdx.y;

  // B fragments: 32 queries of this wave. B[n=lane&31][k=(lane>>5)*8+j], K=16/frag.
  short8 bfrag[8];
  {
    const float* qp = Q + (size_t)(qblock * 128 + wave * 32 + l31) * 128;
#pragma unroll
    for (int kb = 0; kb < 8; kb++) {
      float4 x = *reinterpret_cast<const float4*>(qp + kb * 16 + half * 8);
      float4 y = *reinterpret_cast<const float4*>(qp + kb * 16 + half * 8 + 4);
      short8 b;
      b[0] = (short)f2bf(x.x); b[1] = (short)f2bf(x.y);
      b[2] = (short)f2bf(x.z); b[3] = (short)f2bf(x.w);
      b[4] = (short)f2bf(y.x); b[5] = (short)f2bf(y.y);
      b[6] = (short)f2bf(y.z); b[7] = (short)f2bf(y.w);
      bfrag[kb] = b;
    }
  }

  // Per-lane glds source byte-offsets within a row. Issue i: LDS slot
  // (wave*8+i)*1024B + lane*16B = short index s; v=s>>7, blk8'=(s>>3)&15;
  // source blk8 = blk8' ^ (v&15) -> conflict-free MFMA reads later.
  int goff[8];
#pragma unroll
  for (int i = 0; i < 8; i++) {
    int v = wave * 32 + i * 4 + (lane >> 4);
    int kb = l15 ^ (v & 15);
    goff[i] = v * 256 + kb * 16; // bytes
  }
  const char* chunkbase = (const char*)(T16 + (size_t)(chunk * RC) * (NV * ND));

  // stage row 0 into buf 0
#pragma unroll
  for (int i = 0; i < 8; i++)
    glds16(chunkbase + goff[i], &Blds[0][(wave * 8 + i) * 512 + lane * 8]);
  __syncthreads();

  u64 a[CPC]; // per-lane top-8 for query qblock*128 + wave*32 + l31
#pragma unroll
  for (int i = 0; i < CPC; i++) a[i] = 0;

  const short* abase = &Blds[0][l31 * 128];
  for (int rl = 0; rl < RC; rl++) {
    const int cur = rl & 1;
    if (rl < RC - 1) { // async stage next row into other buffer
      const char* rs = chunkbase + (size_t)(rl + 1) * 32768;
#pragma unroll
      for (int i = 0; i < 8; i++)
        glds16(rs + goff[i], &Blds[1 - cur][(wave * 8 + i) * 512 + lane * 8]);
    }

    float run = -3.402823466e+38f;
#pragma unroll
    for (int t = 0; t < 4; t++) {
      floatx16 acc = 0;
#pragma unroll
      for (int kb = 0; kb < 8; kb++) {
        // A[m=lane&31 -> vector t*32+l31][k=half*8+j]; swizzled block index
        const short* ap = abase + cur * 16384 + t * 4096 +
                          8 * ((kb * 2 + half) ^ (l31 & 15));
        short8 af = *reinterpret_cast<const short8*>(ap);
        acc = __builtin_amdgcn_mfma_f32_32x32x16_bf16(af, bfrag[kb], acc, 0, 0, 0);
      }
      float m = acc[0];
#pragma unroll
      for (int r = 1; r < 16; r++) m = fmaxf(m, acc[r]);
      run = fmaxf(run, m);
    }
    run = fmaxf(run, __shfl_xor(run, 32, 64)); // merge the two v-halves

    u64 x = ((u64)key_of(run) << 32) | (u32)(chunk * RC + rl);
    if (x > a[CPC - 1]) {
#pragma unroll
      for (int p = 0; p < CPC; p++) { // sorted-desc bubble, static indices
        u64 mx = a[p] > x ? a[p] : x;
        u64 mn = a[p] > x ? x : a[p];
        a[p] = mx; x = mn;
      }
    }
    __syncthreads(); // drains glds (issued a full row ago) + guards buffer swap
  }

  if (lane < 32) { // lane owns query; halves are duplicates
    const int q = qblock * 128 + wave * 32 + l31;
    u64* dst = cand + (size_t)q * (NCHUNK * CPC) + chunk * CPC;
#pragma unroll
    for (int i = 0; i < CPC; i++) dst[i] = a[i];
  }
}

// ---------------- K2: wave-per-query merge -> top-24 rows + buckets ----------
__global__ void k2_select(const u64* __restrict__ cand, u64* __restrict__ refined,
                          u32* __restrict__ cnt, u32* __restrict__ bucket) {
  const int q = blockIdx.x;
  const int lane = threadIdx.x;
  const u64* base = cand + (size_t)q * (NCHUNK * CPC);
  u64 a[12];
#pragma unroll
  for (int i = 0; i < 12; i++) a[i] = 0;
  for (int i = 0; i < 32; i++) {
    u64 x = base[i * 64 + lane];
    if (x > a[11]) {
#pragma unroll
      for (int p = 0; p < 12; p++) {
        u64 mx = a[p] > x ? a[p] : x;
        u64 mn = a[p] > x ? x : a[p];
        a[p] = mx; x = mn;
      }
    }
  }
  if (lane < CSEL) refined[(size_t)q * CSEL + lane] = 0; // sentinel for K3

  for (int j = 0; j < CSEL; j++) {
    u64 head = a[0];
    u64 W = head;
#pragma unroll
    for (int off = 1; off < 64; off <<= 1) {
      u64 o = __shfl_xor(W, off, 64);
      if (o > W) W = o;
    }
    if (head == W) { // unique winner lane: pop + emit bucket entry
#pragma unroll
      for (int p = 0; p < 11; p++) a[p] = a[p + 1];
      a[11] = 0;
      u32 row = (u32)W & 4095u;
      u32 slot = atomicAdd(cnt + row, 1u);
      if (slot < BCAP) bucket[(size_t)row * BCAP + slot] = ((u32)q << 5) | (u32)j;
    }
  }
}

// ---------------- K3: exact fp32 refine, bucketed by table row ---------------
// Grid 4096 (one WG per row), 512 threads (4 entries in flight). Row in
// swizzled LDS (64 KiB); q scalarized via readfirstlane -> s_loads.
__global__ void k3_refine(const float* __restrict__ Q, const float* __restrict__ table,
                          const u32* __restrict__ cnt, const u32* __restrict__ bucket,
                          u64* __restrict__ refined) {
  __shared__ float rowv[128 * 128]; // float4 chunk d4 of vec v at (d4 ^ (v&31))
  const int row = blockIdx.x;
  const int tid = threadIdx.x; // 0..511
  u32 n = cnt[row];
  if (n > BCAP) n = BCAP;
  if (n == 0) return;
  const float* src = table + (size_t)row * (NV * ND);
#pragma unroll
  for (int i = 0; i < 8; i++) {
    int idx = i * 2048 + tid * 4;
    int v = idx >> 7;
    int d4 = tid & 31;
    *reinterpret_cast<float4*>(&rowv[v * 128 + ((d4 ^ (v & 31)) << 2)]) =
        *reinterpret_cast<const float4*>(src + idx);
  }
  __syncthreads();
  const int v = tid & 127; // vector owned by this thread
  const int lane = tid & 63;
  const int sw = v & 31;
  for (u32 ei = (u32)(tid >> 7); ei < n; ei += 4) {
    u32 ent = __builtin_amdgcn_readfirstlane(bucket[(size_t)row * BCAP + ei]);
    u32 q = ent >> 5, j = ent & 31u;
    const float* qp = Q + (size_t)q * 128; // uniform -> scalar loads
    float acc = 0.f;
#pragma unroll
    for (int d4 = 0; d4 < 32; d4++) { // strict sequential order (matches ref)
      float4 rv = *reinterpret_cast<const float4*>(&rowv[v * 128 + ((d4 ^ sw) << 2)]);
      acc = fmaf(rv.x, qp[d4 * 4 + 0], acc);
      acc = fmaf(rv.y, qp[d4 * 4 + 1], acc);
      acc = fmaf(rv.z, qp[d4 * 4 + 2], acc);
      acc = fmaf(rv.w, qp[d4 * 4 + 3], acc);
    }
    // wave argmax (smaller v wins ties), then global atomicMax
    u64 p = ((u64)key_of(acc) << 32) | (u32)(127 - v);
#pragma unroll
    for (int off = 1; off < 64; off <<= 1) {
      u64 o = __shfl_xor(p, off, 64);
      if (o > p) p = o;
    }
    if (lane == 0) {
      u32 vbest = 127u - (u32)(p & 0xFFFFFFFFu);
      u64 packed = ((p >> 32) << 32) | (u32)(row * 128 + vbest);
      atomicMax(reinterpret_cast<unsigned long long*>(&refined[(size_t)q * CSEL + j]), packed);
    }
  }
}

// ---------------- K4: sort 24 -> top-16, gather values/scores/ids ------------
__global__ void k4_finalize(const float* __restrict__ table, const u64* __restrict__ refined,
                            float* __restrict__ out) {
  __shared__ u64 arr[CSEL];
  __shared__ u32 fids[KTOP];
  __shared__ float scs[KTOP];
  const int q = blockIdx.x;
  const int tid = threadIdx.x;
  if (tid < CSEL) arr[tid] = refined[(size_t)q * CSEL + tid];
  __syncthreads();
  if (tid == 0) {
    for (int i = 1; i < CSEL; i++) { // insertion sort desc = ref order
      u64 x = arr[i]; int p = i;
      while (p > 0 && arr[p - 1] < x) { arr[p] = arr[p - 1]; p--; }
      arr[p] = x;
    }
    for (int i = 0; i < KTOP; i++) {
      fids[i] = (u32)arr[i];
      scs[i] = unkey((u32)(arr[i] >> 32));
    }
  }
  __syncthreads();
  const int i = tid >> 4, sub = tid & 15;
  const float* src = table + (size_t)fids[i] * 128 + sub * 8;
  float* dst = out + ((size_t)q * KTOP + i) * 128 + sub * 8;
  *reinterpret_cast<float4*>(dst) = *reinterpret_cast<const float4*>(src);
  *reinterpret_cast<float4*>(dst + 4) = *reinterpret_cast<const float4*>(src + 4);
  if (tid < KTOP) {
    out[8388608 + (size_t)q * KTOP + tid] = scs[tid];
    out[8388608 + 65536 + (size_t)q * KTOP + tid] = (float)fids[tid];
  }
}

extern "C" void kernel_launch(void* const* d_in, const int* in_sizes, int n_in,
                              void* d_out, int out_size, void* d_ws, size_t ws_size,
                              hipStream_t stream) {
  (void)in_sizes; (void)n_in; (void)out_size; (void)ws_size;
  const float* Q = (const float*)d_in[0];
  const float* T = (const float*)d_in[1];
  float* out = (float*)d_out;
  char* ws = (char*)d_ws;
  // ws layout (total ~209 MiB)
  unsigned short* T16 = (unsigned short*)ws;                                   // 128 MiB
  u64* cand    = (u64*)(ws + 134217728);                                       //  64 MiB
  u32* cnt     = (u32*)(ws + 134217728 + 67108864);                            //  16 KiB
  u32* bucket  = (u32*)(ws + 134217728 + 67108864 + 16384);                    //  16 MiB
  u64* refined = (u64*)(ws + 134217728 + 67108864 + 16384 + 16777216);         // 768 KiB

  hipMemsetAsync(cnt, 0, NR * sizeof(u32), stream);
  k0_convert<<<65536, 256, 0, stream>>>(T, T16);
  k1_coarse<<<dim3(32, 256), 256, 0, stream>>>(Q, T16, cand);
  k2_select<<<NQ, 64, 0, stream>>>(cand, refined, cnt, bucket);
  k3_refine<<<NR, 512, 0, stream>>>(Q, T, cnt, bucket, refined);
  k4_finalize<<<NQ, 256, 0, stream>>>(T, refined, out);
}